// Round 1
// baseline (518.769 us; speedup 1.0000x reference)
//
#include <hip/hip_runtime.h>
#include <math.h>

// PathFusionEmbedding: B=512, T=100, L=256, D=128, DEPTH=8 (P=9 path nodes).
// Key insight: LSTM runs root->leaf over a binary tree per t; states for
// shared prefixes are identical => compute one LSTM step per TREE NODE
// (T*(2L-1)=51,100 steps, 13.4 GFLOP) instead of per (b,t) sequence (121 GF).
// Heap indexing: node at depth d, pos p has local index 2^d-1+p, parent p>>1.

#define B_N 512
#define T_N 100
#define L_N 256
#define D_N 128
#define NPT 511  // nodes per tree (2L-1)

// ---------------- leaf extraction ----------------
// cross[b, t*256 + l] is one-hot over l (or all-zero -> inactive).
// One 64-lane wave per (b,t) row; each lane checks a float4.
__global__ __launch_bounds__(256) void leaf_kernel(const float* __restrict__ cross,
                                                   int* __restrict__ leaf) {
    const int row  = blockIdx.x * 4 + (threadIdx.x >> 6);  // 4 waves/block
    const int lane = threadIdx.x & 63;
    const float4 v = reinterpret_cast<const float4*>(cross + (size_t)row * L_N)[lane];
    int idx = -1;
    if      (v.x > 0.f) idx = lane * 4 + 0;
    else if (v.y > 0.f) idx = lane * 4 + 1;
    else if (v.z > 0.f) idx = lane * 4 + 2;
    else if (v.w > 0.f) idx = lane * 4 + 3;
    const unsigned long long m = __ballot(idx >= 0);
    if (m == 0ULL) {
        if (lane == 0) leaf[row] = -1;          // inactive
    } else {
        const int first = __builtin_ctzll(m);   // first (lowest-index) hit = argmax
        if (lane == first) leaf[row] = idx;
    }
}

// ---------------- per-level fused LSTM step ----------------
// Block: 256 threads = 16 j-indices x 16 m-threads; tile = 64 nodes x 16 j.
// Each thread: 4 nodes x 4 gates (i,f,g,o) for one hidden index j.
// K = 128 (x from node_emb) + 128 (h from parent level).
__global__ __launch_bounds__(256) void level_kernel(
    const float* __restrict__ node_emb,
    const float* __restrict__ w_ih,
    const float* __restrict__ w_hh,
    const float* __restrict__ b_ih,
    const float* __restrict__ b_hh,
    const float* __restrict__ h_prev,
    const float* __restrict__ c_prev,
    float* __restrict__ h_cur,
    float* __restrict__ c_cur,
    const int d, const int M)
{
    __shared__ float Xs[64][132];   // +4 pad: row stride 132 -> worst 2-way bank alias (free)
    __shared__ float Hs[64][132];

    const int tid = threadIdx.x;
    const int m0  = blockIdx.x * 64;
    const int jt  = tid >> 4;                  // 0..15
    const int mt  = tid & 15;                  // 0..15
    const int j   = blockIdx.y * 16 + jt;      // 0..127
    const bool has_parent = (d > 0);

    // ---- stage X (node_emb rows) and Hp (parent h) into LDS ----
    {
        const int r  = tid >> 2;               // 0..63: tile row
        const int ko = (tid & 3) * 32;         // 4 threads per row, 32 floats each
        const int gm = m0 + r;
        const float4 z4 = make_float4(0.f, 0.f, 0.f, 0.f);
        const float* xsrc = nullptr;
        const float* hsrc = nullptr;
        if (gm < M) {
            const int t     = gm >> d;
            const int p     = gm - (t << d);
            const int local = (1 << d) - 1 + p;
            xsrc = node_emb + (size_t)(t * NPT + local) * D_N;
            if (has_parent) {
                const int gp = t * (1 << (d - 1)) + (p >> 1);
                hsrc = h_prev + (size_t)gp * D_N;
            }
        }
        #pragma unroll
        for (int q = 0; q < 8; ++q) {
            const int k = ko + q * 4;
            const float4 xv = xsrc ? *reinterpret_cast<const float4*>(xsrc + k) : z4;
            const float4 hv = hsrc ? *reinterpret_cast<const float4*>(hsrc + k) : z4;
            *reinterpret_cast<float4*>(&Xs[r][k]) = xv;
            *reinterpret_cast<float4*>(&Hs[r][k]) = hv;
        }
    }
    __syncthreads();

    float acc[4][4];   // [gate i/f/g/o][node n]
    #pragma unroll
    for (int g = 0; g < 4; ++g)
        #pragma unroll
        for (int n = 0; n < 4; ++n) acc[g][n] = 0.f;

    // x-part: gates += x . w_ih[row]
    {
        const float* wi = w_ih + (size_t)(j)       * D_N;
        const float* wf = w_ih + (size_t)(128 + j) * D_N;
        const float* wg = w_ih + (size_t)(256 + j) * D_N;
        const float* wo = w_ih + (size_t)(384 + j) * D_N;
        for (int kc = 0; kc < 32; ++kc) {
            const int k = kc * 4;
            const float4 a = *reinterpret_cast<const float4*>(wi + k);
            const float4 b = *reinterpret_cast<const float4*>(wf + k);
            const float4 c = *reinterpret_cast<const float4*>(wg + k);
            const float4 e = *reinterpret_cast<const float4*>(wo + k);
            #pragma unroll
            for (int n = 0; n < 4; ++n) {
                const float4 xv = *reinterpret_cast<const float4*>(&Xs[mt + n * 16][k]);
                acc[0][n] += a.x * xv.x + a.y * xv.y + a.z * xv.z + a.w * xv.w;
                acc[1][n] += b.x * xv.x + b.y * xv.y + b.z * xv.z + b.w * xv.w;
                acc[2][n] += c.x * xv.x + c.y * xv.y + c.z * xv.z + c.w * xv.w;
                acc[3][n] += e.x * xv.x + e.y * xv.y + e.z * xv.z + e.w * xv.w;
            }
        }
    }
    // h-part: gates += h_parent . w_hh[row]
    if (has_parent) {
        const float* wi = w_hh + (size_t)(j)       * D_N;
        const float* wf = w_hh + (size_t)(128 + j) * D_N;
        const float* wg = w_hh + (size_t)(256 + j) * D_N;
        const float* wo = w_hh + (size_t)(384 + j) * D_N;
        for (int kc = 0; kc < 32; ++kc) {
            const int k = kc * 4;
            const float4 a = *reinterpret_cast<const float4*>(wi + k);
            const float4 b = *reinterpret_cast<const float4*>(wf + k);
            const float4 c = *reinterpret_cast<const float4*>(wg + k);
            const float4 e = *reinterpret_cast<const float4*>(wo + k);
            #pragma unroll
            for (int n = 0; n < 4; ++n) {
                const float4 hv = *reinterpret_cast<const float4*>(&Hs[mt + n * 16][k]);
                acc[0][n] += a.x * hv.x + a.y * hv.y + a.z * hv.z + a.w * hv.w;
                acc[1][n] += b.x * hv.x + b.y * hv.y + b.z * hv.z + b.w * hv.w;
                acc[2][n] += c.x * hv.x + c.y * hv.y + c.z * hv.z + c.w * hv.w;
                acc[3][n] += e.x * hv.x + e.y * hv.y + e.z * hv.z + e.w * hv.w;
            }
        }
    }

    // ---- LSTM epilogue ----
    const float bi = b_ih[j]       + b_hh[j];
    const float bf = b_ih[128 + j] + b_hh[128 + j];
    const float bg = b_ih[256 + j] + b_hh[256 + j];
    const float bo = b_ih[384 + j] + b_hh[384 + j];

    #pragma unroll
    for (int n = 0; n < 4; ++n) {
        const int gm = m0 + mt + n * 16;
        if (gm < M) {
            const float ig = 1.f / (1.f + expf(-(acc[0][n] + bi)));
            const float fg = 1.f / (1.f + expf(-(acc[1][n] + bf)));
            const float gg = tanhf(acc[2][n] + bg);
            const float og = 1.f / (1.f + expf(-(acc[3][n] + bo)));
            float cp = 0.f;
            if (has_parent) {
                const int t  = gm >> d;
                const int p  = gm - (t << d);
                const int gp = t * (1 << (d - 1)) + (p >> 1);
                cp = c_prev[(size_t)gp * D_N + j];
            }
            const float cn = fg * cp + ig * gg;
            const float hn = og * tanhf(cn);
            c_cur[(size_t)gm * D_N + j] = cn;
            h_cur[(size_t)gm * D_N + j] = hn;
        }
    }
}

// ---------------- final gather ----------------
// out[b,t,:] = active ? h_level8[t*256 + leaf, :] : 0
__global__ __launch_bounds__(256) void gather_kernel(const float* __restrict__ h8,
                                                     const int* __restrict__ leaf,
                                                     float* __restrict__ out) {
    const int idx = blockIdx.x * 256 + threadIdx.x;   // one float4 per thread
    const int k4  = idx & 31;
    const int bt  = idx >> 5;
    const int t   = bt % T_N;
    const int lf  = leaf[bt];
    float4 v = make_float4(0.f, 0.f, 0.f, 0.f);
    if (lf >= 0)
        v = reinterpret_cast<const float4*>(h8 + (size_t)(t * L_N + lf) * D_N)[k4];
    reinterpret_cast<float4*>(out)[idx] = v;
}

extern "C" void kernel_launch(void* const* d_in, const int* in_sizes, int n_in,
                              void* d_out, int out_size, void* d_ws, size_t ws_size,
                              hipStream_t stream) {
    const float* cross    = (const float*)d_in[0];
    const float* node_emb = (const float*)d_in[1];
    const float* w_ih     = (const float*)d_in[2];
    const float* w_hh     = (const float*)d_in[3];
    const float* b_ih     = (const float*)d_in[4];
    const float* b_hh     = (const float*)d_in[5];
    // d_in[6] (paths) unused: heap indexing reproduces it exactly.
    float* out = (float*)d_out;
    float* ws  = (float*)d_ws;

    // ws layout (fp32): h ping-pong [2][25600*128], c ping-pong [2][25600*128], leaf[51200]
    // total = 52.6 MB
    const size_t LVL = (size_t)25600 * D_N;
    float* hb[2] = { ws,           ws + LVL     };
    float* cb[2] = { ws + 2 * LVL, ws + 3 * LVL };
    int*   leaf  = (int*)(ws + 4 * LVL);

    leaf_kernel<<<(B_N * T_N) / 4, 256, 0, stream>>>(cross, leaf);

    for (int d = 0; d <= 8; ++d) {
        const int M = T_N << d;
        const int cur = d & 1, prev = cur ^ 1;
        dim3 grid((M + 63) / 64, D_N / 16);
        level_kernel<<<grid, 256, 0, stream>>>(node_emb, w_ih, w_hh, b_ih, b_hh,
                                               hb[prev], cb[prev], hb[cur], cb[cur],
                                               d, M);
    }
    // d=8 wrote hb[0]
    gather_kernel<<<(B_N * T_N * (D_N / 4)) / 256, 256, 0, stream>>>(hb[0], leaf, out);
}

// Round 2
// 325.159 us; speedup vs baseline: 1.5954x; 1.5954x over previous
//
#include <hip/hip_runtime.h>
#include <math.h>

// PathFusionEmbedding: B=512, T=100, L=256, D=128, DEPTH=8 (P=9).
// Tree-structured LSTM: one step per tree node (heap indexing, parent = m>>1).
// Levels 0..5: fp32 vector kernel. Levels 6..8: split-bf16 MFMA kernel
// (h*W = hh*Wh + hh*Wl + hl*Wh; x*W single-term bf16) -> fp32-grade accuracy
// at bf16-MFMA rate.

#define B_N 512
#define T_N 100
#define L_N 256
#define D_N 128
#define NPT 511

typedef __attribute__((ext_vector_type(8))) short short8;
typedef __attribute__((ext_vector_type(4))) float f32x4;
typedef __attribute__((ext_vector_type(4))) unsigned short ushort4v;

__device__ __forceinline__ unsigned short f2bf(float f) {
    unsigned u = __float_as_uint(f);
    return (unsigned short)((u + 0x7FFFu + ((u >> 16) & 1u)) >> 16);
}
__device__ __forceinline__ float bf2f(unsigned short b) {
    return __uint_as_float(((unsigned)b) << 16);
}

// ---------------- weight pack + bias prep ----------------
// W'[n'][k] = k<128 ? w_ih[n'][k] : w_hh[n'][k-128]   (n' = gate*128 + j)
// Packed into exact 16x16x32 B-fragment order:
//   B[k][n']: kb=k>>5, krel=k&31, quad=krel>>3, e=krel&7, tn=n'>>4, col=n'&15
//   lane = quad*16+col; Bhi[((kb*32+tn)*64+lane)*8+e]
// Blo only for k>=128 (the h-part), indexed with kb-4.
__global__ __launch_bounds__(256) void pack_kernel(const float* __restrict__ w_ih,
                                                   const float* __restrict__ w_hh,
                                                   const float* __restrict__ b_ih,
                                                   const float* __restrict__ b_hh,
                                                   unsigned short* __restrict__ Bhi,
                                                   unsigned short* __restrict__ Blo,
                                                   float* __restrict__ bias) {
    const int idx = blockIdx.x * 256 + threadIdx.x;   // 131072 = 512 n' x 256 k
    const int k  = idx & 255;
    const int np = idx >> 8;
    const float val = (k < 128) ? w_ih[(size_t)np * 128 + k]
                                : w_hh[(size_t)np * 128 + (k - 128)];
    const unsigned short hi = f2bf(val);
    const int kb = k >> 5, krel = k & 31, quad = krel >> 3, e = krel & 7;
    const int tn = np >> 4, col = np & 15, lane = quad * 16 + col;
    Bhi[(((size_t)kb * 32 + tn) * 64 + lane) * 8 + e] = hi;
    if (kb >= 4) {
        const unsigned short lo = f2bf(val - bf2f(hi));
        Blo[((((size_t)kb - 4) * 32 + tn) * 64 + lane) * 8 + e] = lo;
    }
    if (k == 0) bias[np] = b_ih[np] + b_hh[np];
}

// ---------------- leaf extraction ----------------
__global__ __launch_bounds__(256) void leaf_kernel(const float* __restrict__ cross,
                                                   int* __restrict__ leaf) {
    const int row  = blockIdx.x * 4 + (threadIdx.x >> 6);
    const int lane = threadIdx.x & 63;
    const float4 v = reinterpret_cast<const float4*>(cross + (size_t)row * L_N)[lane];
    int idx = -1;
    if      (v.x > 0.f) idx = lane * 4 + 0;
    else if (v.y > 0.f) idx = lane * 4 + 1;
    else if (v.z > 0.f) idx = lane * 4 + 2;
    else if (v.w > 0.f) idx = lane * 4 + 3;
    const unsigned long long m = __ballot(idx >= 0);
    if (m == 0ULL) {
        if (lane == 0) leaf[row] = -1;
    } else {
        const int first = __builtin_ctzll(m);
        if (lane == first) leaf[row] = idx;
    }
}

// ---------------- fp32 level kernel (small levels d=0..5) ----------------
__global__ __launch_bounds__(256) void level_kernel(
    const float* __restrict__ node_emb,
    const float* __restrict__ w_ih,
    const float* __restrict__ w_hh,
    const float* __restrict__ b_ih,
    const float* __restrict__ b_hh,
    const float* __restrict__ h_prev,
    const float* __restrict__ c_prev,
    float* __restrict__ h_cur,
    float* __restrict__ c_cur,
    const int d, const int M)
{
    __shared__ float Xs[64][132];
    __shared__ float Hs[64][132];

    const int tid = threadIdx.x;
    const int m0  = blockIdx.x * 64;
    const int jt  = tid >> 4;
    const int mt  = tid & 15;
    const int j   = blockIdx.y * 16 + jt;
    const bool has_parent = (d > 0);

    {
        const int r  = tid >> 2;
        const int ko = (tid & 3) * 32;
        const int gm = m0 + r;
        const float4 z4 = make_float4(0.f, 0.f, 0.f, 0.f);
        const float* xsrc = nullptr;
        const float* hsrc = nullptr;
        if (gm < M) {
            const int t     = gm >> d;
            const int p     = gm - (t << d);
            const int local = (1 << d) - 1 + p;
            xsrc = node_emb + (size_t)(t * NPT + local) * D_N;
            if (has_parent) hsrc = h_prev + (size_t)(gm >> 1) * D_N;
        }
        #pragma unroll
        for (int q = 0; q < 8; ++q) {
            const int k = ko + q * 4;
            const float4 xv = xsrc ? *reinterpret_cast<const float4*>(xsrc + k) : z4;
            const float4 hv = hsrc ? *reinterpret_cast<const float4*>(hsrc + k) : z4;
            *reinterpret_cast<float4*>(&Xs[r][k]) = xv;
            *reinterpret_cast<float4*>(&Hs[r][k]) = hv;
        }
    }
    __syncthreads();

    float acc[4][4];
    #pragma unroll
    for (int g = 0; g < 4; ++g)
        #pragma unroll
        for (int n = 0; n < 4; ++n) acc[g][n] = 0.f;

    {
        const float* wi = w_ih + (size_t)(j)       * D_N;
        const float* wf = w_ih + (size_t)(128 + j) * D_N;
        const float* wg = w_ih + (size_t)(256 + j) * D_N;
        const float* wo = w_ih + (size_t)(384 + j) * D_N;
        for (int kc = 0; kc < 32; ++kc) {
            const int k = kc * 4;
            const float4 a = *reinterpret_cast<const float4*>(wi + k);
            const float4 b = *reinterpret_cast<const float4*>(wf + k);
            const float4 c = *reinterpret_cast<const float4*>(wg + k);
            const float4 e = *reinterpret_cast<const float4*>(wo + k);
            #pragma unroll
            for (int n = 0; n < 4; ++n) {
                const float4 xv = *reinterpret_cast<const float4*>(&Xs[mt + n * 16][k]);
                acc[0][n] += a.x * xv.x + a.y * xv.y + a.z * xv.z + a.w * xv.w;
                acc[1][n] += b.x * xv.x + b.y * xv.y + b.z * xv.z + b.w * xv.w;
                acc[2][n] += c.x * xv.x + c.y * xv.y + c.z * xv.z + c.w * xv.w;
                acc[3][n] += e.x * xv.x + e.y * xv.y + e.z * xv.z + e.w * xv.w;
            }
        }
    }
    if (has_parent) {
        const float* wi = w_hh + (size_t)(j)       * D_N;
        const float* wf = w_hh + (size_t)(128 + j) * D_N;
        const float* wg = w_hh + (size_t)(256 + j) * D_N;
        const float* wo = w_hh + (size_t)(384 + j) * D_N;
        for (int kc = 0; kc < 32; ++kc) {
            const int k = kc * 4;
            const float4 a = *reinterpret_cast<const float4*>(wi + k);
            const float4 b = *reinterpret_cast<const float4*>(wf + k);
            const float4 c = *reinterpret_cast<const float4*>(wg + k);
            const float4 e = *reinterpret_cast<const float4*>(wo + k);
            #pragma unroll
            for (int n = 0; n < 4; ++n) {
                const float4 hv = *reinterpret_cast<const float4*>(&Hs[mt + n * 16][k]);
                acc[0][n] += a.x * hv.x + a.y * hv.y + a.z * hv.z + a.w * hv.w;
                acc[1][n] += b.x * hv.x + b.y * hv.y + b.z * hv.z + b.w * hv.w;
                acc[2][n] += c.x * hv.x + c.y * hv.y + c.z * hv.z + c.w * hv.w;
                acc[3][n] += e.x * hv.x + e.y * hv.y + e.z * hv.z + e.w * hv.w;
            }
        }
    }

    const float bi = b_ih[j]       + b_hh[j];
    const float bf = b_ih[128 + j] + b_hh[128 + j];
    const float bg = b_ih[256 + j] + b_hh[256 + j];
    const float bo = b_ih[384 + j] + b_hh[384 + j];

    #pragma unroll
    for (int n = 0; n < 4; ++n) {
        const int gm = m0 + mt + n * 16;
        if (gm < M) {
            const float ig = 1.f / (1.f + expf(-(acc[0][n] + bi)));
            const float fg = 1.f / (1.f + expf(-(acc[1][n] + bf)));
            const float gg = tanhf(acc[2][n] + bg);
            const float og = 1.f / (1.f + expf(-(acc[3][n] + bo)));
            float cp = 0.f;
            if (has_parent) cp = c_prev[(size_t)(gm >> 1) * D_N + j];
            const float cn = fg * cp + ig * gg;
            const float hn = og * tanhf(cn);
            c_cur[(size_t)gm * D_N + j] = cn;
            h_cur[(size_t)gm * D_N + j] = hn;
        }
    }
}

// ---------------- MFMA level kernel (d=6,7,8; M % 64 == 0) ----------------
// Block: 256 threads = 4 waves. Block tile: 64 nodes x 512 gates.
// Wave w: j-range [32w, 32w+32) for ALL 4 gates -> acc[4 mt][2 jt][4 g].
// A = [x | h_parent] staged hi/lo bf16 in LDS; B pre-packed in fragment order.
__global__ __launch_bounds__(256, 2) void mfma_level_kernel(
    const float* __restrict__ node_emb,
    const unsigned short* __restrict__ Bhi,
    const unsigned short* __restrict__ Blo,
    const float* __restrict__ bias,
    const float* __restrict__ h_prev,
    const float* __restrict__ c_prev,
    float* __restrict__ h_cur,
    float* __restrict__ c_cur,
    const int d)
{
    __shared__ unsigned short Ahi[64 * 264];   // [m][k 0..255], stride 264 (pad 8)
    __shared__ unsigned short Alo[64 * 136];   // [m][k 128..255], stride 136

    const int tid = threadIdx.x;
    const int m0  = blockIdx.x * 64;

    // ---- stage A ----
    {
        const int r  = tid >> 2;     // 0..63: tile row
        const int q  = tid & 3;      // quarter: 64 floats each
        const int gm = m0 + r;
        if (q < 2) {
            const int t     = gm >> d;
            const int p     = gm - (t << d);
            const int local = (1 << d) - 1 + p;
            const float4* src = reinterpret_cast<const float4*>(
                node_emb + (size_t)(t * NPT + local) * D_N + q * 64);
            #pragma unroll
            for (int i = 0; i < 16; ++i) {
                const float4 v = src[i];
                ushort4v hv = { f2bf(v.x), f2bf(v.y), f2bf(v.z), f2bf(v.w) };
                *reinterpret_cast<ushort4v*>(&Ahi[r * 264 + q * 64 + i * 4]) = hv;
            }
        } else {
            const float4* src = reinterpret_cast<const float4*>(
                h_prev + (size_t)(gm >> 1) * D_N + (q - 2) * 64);
            #pragma unroll
            for (int i = 0; i < 16; ++i) {
                const float4 v = src[i];
                ushort4v hv = { f2bf(v.x), f2bf(v.y), f2bf(v.z), f2bf(v.w) };
                ushort4v lv = { f2bf(v.x - bf2f(hv.x)), f2bf(v.y - bf2f(hv.y)),
                                f2bf(v.z - bf2f(hv.z)), f2bf(v.w - bf2f(hv.w)) };
                const int kx = (q - 2) * 64 + i * 4;
                *reinterpret_cast<ushort4v*>(&Ahi[r * 264 + 128 + kx]) = hv;
                *reinterpret_cast<ushort4v*>(&Alo[r * 136 + kx])       = lv;
            }
        }
    }
    __syncthreads();

    const int w    = tid >> 6;       // wave 0..3
    const int lane = tid & 63;
    const int ml   = lane & 15;
    const int quad = lane >> 4;

    f32x4 acc[4][2][4];              // [mt][jt][gate]
    #pragma unroll
    for (int mt = 0; mt < 4; ++mt)
        #pragma unroll
        for (int jt = 0; jt < 2; ++jt)
            #pragma unroll
            for (int g = 0; g < 4; ++g) acc[mt][jt][g] = (f32x4)0.f;

    const short8* Bh8 = reinterpret_cast<const short8*>(Bhi);
    const short8* Bl8 = reinterpret_cast<const short8*>(Blo);

    #pragma unroll
    for (int kb = 0; kb < 8; ++kb) {
        short8 Ah[4], Al[4];
        #pragma unroll
        for (int mt = 0; mt < 4; ++mt)
            Ah[mt] = *reinterpret_cast<const short8*>(
                &Ahi[(mt * 16 + ml) * 264 + kb * 32 + quad * 8]);
        if (kb >= 4) {
            #pragma unroll
            for (int mt = 0; mt < 4; ++mt)
                Al[mt] = *reinterpret_cast<const short8*>(
                    &Alo[(mt * 16 + ml) * 136 + (kb - 4) * 32 + quad * 8]);
        }
        #pragma unroll
        for (int jt = 0; jt < 2; ++jt) {
            #pragma unroll
            for (int g = 0; g < 4; ++g) {
                const int tn = g * 8 + 2 * w + jt;
                const short8 Bh = Bh8[(kb * 32 + tn) * 64 + lane];
                if (kb < 4) {
                    #pragma unroll
                    for (int mt = 0; mt < 4; ++mt)
                        acc[mt][jt][g] = __builtin_amdgcn_mfma_f32_16x16x32_bf16(
                            Ah[mt], Bh, acc[mt][jt][g], 0, 0, 0);
                } else {
                    const short8 Bl = Bl8[((kb - 4) * 32 + tn) * 64 + lane];
                    #pragma unroll
                    for (int mt = 0; mt < 4; ++mt) {
                        acc[mt][jt][g] = __builtin_amdgcn_mfma_f32_16x16x32_bf16(
                            Ah[mt], Bh, acc[mt][jt][g], 0, 0, 0);
                        acc[mt][jt][g] = __builtin_amdgcn_mfma_f32_16x16x32_bf16(
                            Ah[mt], Bl, acc[mt][jt][g], 0, 0, 0);
                        acc[mt][jt][g] = __builtin_amdgcn_mfma_f32_16x16x32_bf16(
                            Al[mt], Bh, acc[mt][jt][g], 0, 0, 0);
                    }
                }
            }
        }
    }

    // ---- fused LSTM epilogue ----
    // C/D layout: row = quad*4 + r, col = lane&15 (row->node, col->j within tile)
    #pragma unroll
    for (int jt = 0; jt < 2; ++jt) {
        const int j  = 32 * w + jt * 16 + ml;
        const float bi = bias[j];
        const float bf = bias[128 + j];
        const float bg = bias[256 + j];
        const float bo = bias[384 + j];
        #pragma unroll
        for (int mt = 0; mt < 4; ++mt) {
            #pragma unroll
            for (int r = 0; r < 4; ++r) {
                const int m = m0 + mt * 16 + quad * 4 + r;
                const float gi = acc[mt][jt][0][r] + bi;
                const float gf = acc[mt][jt][1][r] + bf;
                const float gg = acc[mt][jt][2][r] + bg;
                const float go = acc[mt][jt][3][r] + bo;
                const float ig = 1.f / (1.f + expf(-gi));
                const float fg = 1.f / (1.f + expf(-gf));
                const float gv = tanhf(gg);
                const float og = 1.f / (1.f + expf(-go));
                const float cp = c_prev[(size_t)(m >> 1) * D_N + j];
                const float cn = fg * cp + ig * gv;
                const float hn = og * tanhf(cn);
                c_cur[(size_t)m * D_N + j] = cn;
                h_cur[(size_t)m * D_N + j] = hn;
            }
        }
    }
}

// ---------------- final gather ----------------
__global__ __launch_bounds__(256) void gather_kernel(const float* __restrict__ h8,
                                                     const int* __restrict__ leaf,
                                                     float* __restrict__ out) {
    const int idx = blockIdx.x * 256 + threadIdx.x;
    const int k4  = idx & 31;
    const int bt  = idx >> 5;
    const int t   = bt % T_N;
    const int lf  = leaf[bt];
    float4 v = make_float4(0.f, 0.f, 0.f, 0.f);
    if (lf >= 0)
        v = reinterpret_cast<const float4*>(h8 + (size_t)(t * L_N + lf) * D_N)[k4];
    reinterpret_cast<float4*>(out)[idx] = v;
}

extern "C" void kernel_launch(void* const* d_in, const int* in_sizes, int n_in,
                              void* d_out, int out_size, void* d_ws, size_t ws_size,
                              hipStream_t stream) {
    const float* cross    = (const float*)d_in[0];
    const float* node_emb = (const float*)d_in[1];
    const float* w_ih     = (const float*)d_in[2];
    const float* w_hh     = (const float*)d_in[3];
    const float* b_ih     = (const float*)d_in[4];
    const float* b_hh     = (const float*)d_in[5];
    float* out = (float*)d_out;
    float* ws  = (float*)d_ws;

    // ws layout (floats):
    //   hA[25600*128] cA[25600*128] hB[12800*128] cB[12800*128]
    //   leaf[51200(int)] bias[512] Bhi[131072 u16 = 65536 f] Blo[65536 u16 = 32768 f]
    const size_t SA = (size_t)25600 * D_N;     // 3,276,800
    const size_t SB = (size_t)12800 * D_N;     // 1,638,400
    float* hA = ws;
    float* cA = hA + SA;
    float* hB = cA + SA;
    float* cB = hB + SB;
    int*   leaf = (int*)(cB + SB);
    float* bias = (float*)(leaf + 51200);
    unsigned short* Bhi = (unsigned short*)(bias + 512);
    unsigned short* Blo = Bhi + 131072;

    pack_kernel<<<512, 256, 0, stream>>>(w_ih, w_hh, b_ih, b_hh, Bhi, Blo, bias);
    leaf_kernel<<<(B_N * T_N) / 4, 256, 0, stream>>>(cross, leaf);

    // levels 0..5: fp32 vector kernel (even d -> A buffers, odd d -> B buffers)
    for (int d = 0; d <= 5; ++d) {
        const int M = T_N << d;
        float* hc = (d & 1) ? hB : hA;
        float* cc = (d & 1) ? cB : cA;
        float* hp = (d & 1) ? hA : hB;
        float* cp = (d & 1) ? cA : cB;
        dim3 grid((M + 63) / 64, D_N / 16);
        level_kernel<<<grid, 256, 0, stream>>>(node_emb, w_ih, w_hh, b_ih, b_hh,
                                               hp, cp, hc, cc, d, M);
    }
    // levels 6..8: MFMA split-bf16 kernel
    for (int d = 6; d <= 8; ++d) {
        const int M = T_N << d;
        float* hc = (d & 1) ? hB : hA;
        float* cc = (d & 1) ? cB : cA;
        float* hp = (d & 1) ? hA : hB;
        float* cp = (d & 1) ? cA : cB;
        mfma_level_kernel<<<M / 64, 256, 0, stream>>>(node_emb, Bhi, Blo, bias,
                                                      hp, cp, hc, cc, d);
    }
    // d=8 wrote hA
    gather_kernel<<<(B_N * T_N * (D_N / 4)) / 256, 256, 0, stream>>>(hA, leaf, out);
}

// Round 3
// 308.782 us; speedup vs baseline: 1.6801x; 1.0530x over previous
//
#include <hip/hip_runtime.h>
#include <math.h>

// PathFusionEmbedding: B=512, T=100, L=256, D=128, DEPTH=8 (P=9).
// Tree-structured LSTM: one step per tree node (heap indexing, parent = m>>1).
// Levels 0..4: fp32 vector kernel. Levels 5..8: split-bf16 MFMA kernel
// (h*W = hh*Wh + hh*Wl + hl*Wh; x*W single-term bf16) -> fp32-grade accuracy.
// R3: 32-node MFMA blocks (2x grid), 64-AGPR acc/wave, fragment-major A in LDS
// (conflict-free ds_read_b128), B pipelined from L2, fast exp2/rcp epilogue.

#define B_N 512
#define T_N 100
#define L_N 256
#define D_N 128
#define NPT 511

typedef __attribute__((ext_vector_type(8))) short short8;
typedef __attribute__((ext_vector_type(4))) float f32x4;
typedef __attribute__((ext_vector_type(4))) unsigned short ushort4v;

__device__ __forceinline__ unsigned short f2bf(float f) {
    unsigned u = __float_as_uint(f);
    return (unsigned short)((u + 0x7FFFu + ((u >> 16) & 1u)) >> 16);
}
__device__ __forceinline__ float bf2f(unsigned short b) {
    return __uint_as_float(((unsigned)b) << 16);
}
// fast sigmoid/tanh: v_exp_f32 computes 2^x; v_rcp_f32 ~1ulp.
__device__ __forceinline__ float fsigmoid(float x) {
    return __builtin_amdgcn_rcpf(1.f + __builtin_amdgcn_exp2f(-1.44269504f * x));
}
__device__ __forceinline__ float ftanh(float x) {
    return 1.f - 2.f * __builtin_amdgcn_rcpf(1.f + __builtin_amdgcn_exp2f(2.88539009f * x));
}

// ---------------- weight pack + bias prep ----------------
// W'[n'][k] = k<128 ? w_ih[n'][k] : w_hh[n'][k-128]   (n' = gate*128 + j)
// B-fragment order: kb=k>>5, krel=k&31, quad=krel>>3, e=krel&7, tn=n'>>4,
// lane=quad*16+(n'&15); Bhi[((kb*32+tn)*64+lane)*8+e]. Blo for k>=128 only.
__global__ __launch_bounds__(256) void pack_kernel(const float* __restrict__ w_ih,
                                                   const float* __restrict__ w_hh,
                                                   const float* __restrict__ b_ih,
                                                   const float* __restrict__ b_hh,
                                                   unsigned short* __restrict__ Bhi,
                                                   unsigned short* __restrict__ Blo,
                                                   float* __restrict__ bias) {
    const int idx = blockIdx.x * 256 + threadIdx.x;   // 131072 = 512 n' x 256 k
    const int k  = idx & 255;
    const int np = idx >> 8;
    const float val = (k < 128) ? w_ih[(size_t)np * 128 + k]
                                : w_hh[(size_t)np * 128 + (k - 128)];
    const unsigned short hi = f2bf(val);
    const int kb = k >> 5, krel = k & 31, quad = krel >> 3, e = krel & 7;
    const int tn = np >> 4, col = np & 15, lane = quad * 16 + col;
    Bhi[(((size_t)kb * 32 + tn) * 64 + lane) * 8 + e] = hi;
    if (kb >= 4) {
        const unsigned short lo = f2bf(val - bf2f(hi));
        Blo[((((size_t)kb - 4) * 32 + tn) * 64 + lane) * 8 + e] = lo;
    }
    if (k == 0) bias[np] = b_ih[np] + b_hh[np];
}

// ---------------- leaf extraction ----------------
__global__ __launch_bounds__(256) void leaf_kernel(const float* __restrict__ cross,
                                                   int* __restrict__ leaf) {
    const int row  = blockIdx.x * 4 + (threadIdx.x >> 6);
    const int lane = threadIdx.x & 63;
    const float4 v = reinterpret_cast<const float4*>(cross + (size_t)row * L_N)[lane];
    int idx = -1;
    if      (v.x > 0.f) idx = lane * 4 + 0;
    else if (v.y > 0.f) idx = lane * 4 + 1;
    else if (v.z > 0.f) idx = lane * 4 + 2;
    else if (v.w > 0.f) idx = lane * 4 + 3;
    const unsigned long long m = __ballot(idx >= 0);
    if (m == 0ULL) {
        if (lane == 0) leaf[row] = -1;
    } else {
        const int first = __builtin_ctzll(m);
        if (lane == first) leaf[row] = idx;
    }
}

// ---------------- fp32 level kernel (d = 0..4) ----------------
__global__ __launch_bounds__(256) void level_kernel(
    const float* __restrict__ node_emb,
    const float* __restrict__ w_ih,
    const float* __restrict__ w_hh,
    const float* __restrict__ b_ih,
    const float* __restrict__ b_hh,
    const float* __restrict__ h_prev,
    const float* __restrict__ c_prev,
    float* __restrict__ h_cur,
    float* __restrict__ c_cur,
    const int d, const int M)
{
    __shared__ float Xs[64][132];
    __shared__ float Hs[64][132];

    const int tid = threadIdx.x;
    const int m0  = blockIdx.x * 64;
    const int jt  = tid >> 4;
    const int mt  = tid & 15;
    const int j   = blockIdx.y * 16 + jt;
    const bool has_parent = (d > 0);

    {
        const int r  = tid >> 2;
        const int ko = (tid & 3) * 32;
        const int gm = m0 + r;
        const float4 z4 = make_float4(0.f, 0.f, 0.f, 0.f);
        const float* xsrc = nullptr;
        const float* hsrc = nullptr;
        if (gm < M) {
            const int t     = gm >> d;
            const int p     = gm - (t << d);
            const int local = (1 << d) - 1 + p;
            xsrc = node_emb + (size_t)(t * NPT + local) * D_N;
            if (has_parent) hsrc = h_prev + (size_t)(gm >> 1) * D_N;
        }
        #pragma unroll
        for (int q = 0; q < 8; ++q) {
            const int k = ko + q * 4;
            const float4 xv = xsrc ? *reinterpret_cast<const float4*>(xsrc + k) : z4;
            const float4 hv = hsrc ? *reinterpret_cast<const float4*>(hsrc + k) : z4;
            *reinterpret_cast<float4*>(&Xs[r][k]) = xv;
            *reinterpret_cast<float4*>(&Hs[r][k]) = hv;
        }
    }
    __syncthreads();

    float acc[4][4];
    #pragma unroll
    for (int g = 0; g < 4; ++g)
        #pragma unroll
        for (int n = 0; n < 4; ++n) acc[g][n] = 0.f;

    {
        const float* wi = w_ih + (size_t)(j)       * D_N;
        const float* wf = w_ih + (size_t)(128 + j) * D_N;
        const float* wg = w_ih + (size_t)(256 + j) * D_N;
        const float* wo = w_ih + (size_t)(384 + j) * D_N;
        for (int kc = 0; kc < 32; ++kc) {
            const int k = kc * 4;
            const float4 a = *reinterpret_cast<const float4*>(wi + k);
            const float4 b = *reinterpret_cast<const float4*>(wf + k);
            const float4 c = *reinterpret_cast<const float4*>(wg + k);
            const float4 e = *reinterpret_cast<const float4*>(wo + k);
            #pragma unroll
            for (int n = 0; n < 4; ++n) {
                const float4 xv = *reinterpret_cast<const float4*>(&Xs[mt + n * 16][k]);
                acc[0][n] += a.x * xv.x + a.y * xv.y + a.z * xv.z + a.w * xv.w;
                acc[1][n] += b.x * xv.x + b.y * xv.y + b.z * xv.z + b.w * xv.w;
                acc[2][n] += c.x * xv.x + c.y * xv.y + c.z * xv.z + c.w * xv.w;
                acc[3][n] += e.x * xv.x + e.y * xv.y + e.z * xv.z + e.w * xv.w;
            }
        }
    }
    if (has_parent) {
        const float* wi = w_hh + (size_t)(j)       * D_N;
        const float* wf = w_hh + (size_t)(128 + j) * D_N;
        const float* wg = w_hh + (size_t)(256 + j) * D_N;
        const float* wo = w_hh + (size_t)(384 + j) * D_N;
        for (int kc = 0; kc < 32; ++kc) {
            const int k = kc * 4;
            const float4 a = *reinterpret_cast<const float4*>(wi + k);
            const float4 b = *reinterpret_cast<const float4*>(wf + k);
            const float4 c = *reinterpret_cast<const float4*>(wg + k);
            const float4 e = *reinterpret_cast<const float4*>(wo + k);
            #pragma unroll
            for (int n = 0; n < 4; ++n) {
                const float4 hv = *reinterpret_cast<const float4*>(&Hs[mt + n * 16][k]);
                acc[0][n] += a.x * hv.x + a.y * hv.y + a.z * hv.z + a.w * hv.w;
                acc[1][n] += b.x * hv.x + b.y * hv.y + b.z * hv.z + b.w * hv.w;
                acc[2][n] += c.x * hv.x + c.y * hv.y + c.z * hv.z + c.w * hv.w;
                acc[3][n] += e.x * hv.x + e.y * hv.y + e.z * hv.z + e.w * hv.w;
            }
        }
    }

    const float bi = b_ih[j]       + b_hh[j];
    const float bf = b_ih[128 + j] + b_hh[128 + j];
    const float bg = b_ih[256 + j] + b_hh[256 + j];
    const float bo = b_ih[384 + j] + b_hh[384 + j];

    #pragma unroll
    for (int n = 0; n < 4; ++n) {
        const int gm = m0 + mt + n * 16;
        if (gm < M) {
            const float ig = fsigmoid(acc[0][n] + bi);
            const float fg = fsigmoid(acc[1][n] + bf);
            const float gg = ftanh(acc[2][n] + bg);
            const float og = fsigmoid(acc[3][n] + bo);
            float cp = 0.f;
            if (has_parent) cp = c_prev[(size_t)(gm >> 1) * D_N + j];
            const float cn = fg * cp + ig * gg;
            const float hn = og * ftanh(cn);
            c_cur[(size_t)gm * D_N + j] = cn;
            h_cur[(size_t)gm * D_N + j] = hn;
        }
    }
}

// ---------------- MFMA level kernel (d=5..8; M % 32 == 0) ----------------
// Block: 256 threads = 4 waves; tile = 32 nodes x 512 gates.
// Wave w: tn = g*8 + 2w + jt (jt=0..1, g=0..3), mt=0..1 -> 16 C-tiles (64 AGPR).
// A staged in LDS in FRAGMENT-MAJOR order: frag (kb,mt) at [(kb*2+mt)*64+lane]*8
// -> ds_read_b128 at base+lane*16: conflict-free. B streamed from L2 (384 KB
// total, L2-resident), ~70 spare VGPRs keep loads in flight.
__global__ __launch_bounds__(256, 3) void mfma_level_kernel(
    const float* __restrict__ node_emb,
    const unsigned short* __restrict__ Bhi,
    const unsigned short* __restrict__ Blo,
    const float* __restrict__ bias,
    const float* __restrict__ h_prev,
    const float* __restrict__ c_prev,
    float* __restrict__ h_cur,
    float* __restrict__ c_cur,
    const int d)
{
    __shared__ unsigned short AhiF[8 * 2 * 512];   // [kb][mt][lane*8+e]  16 KB
    __shared__ unsigned short AloF[4 * 2 * 512];   // [kb-4][mt][...]      8 KB

    const int tid = threadIdx.x;
    const int m0  = blockIdx.x * 32;

    // ---- stage A: thread (r = tid>>3, q = tid&7) covers row r, kb = q ----
    {
        const int r  = tid >> 3;         // 0..31 node row
        const int q  = tid & 7;          // kb
        const int gm = m0 + r;
        const int mt = r >> 4, ml = r & 15;
        const float* src;
        if (q < 4) {
            const int t     = gm >> d;
            const int p     = gm - (t << d);
            const int local = (1 << d) - 1 + p;
            src = node_emb + (size_t)(t * NPT + local) * D_N + q * 32;
        } else {
            src = h_prev + (size_t)(gm >> 1) * D_N + (q - 4) * 32;
        }
        #pragma unroll
        for (int i = 0; i < 8; ++i) {
            const float4 v = reinterpret_cast<const float4*>(src)[i];
            const ushort4v hv = { f2bf(v.x), f2bf(v.y), f2bf(v.z), f2bf(v.w) };
            const int fo = ((q * 2 + mt) * 64 + (i >> 1) * 16 + ml) * 8 + (i & 1) * 4;
            *reinterpret_cast<ushort4v*>(&AhiF[fo]) = hv;
            if (q >= 4) {
                const ushort4v lv = { f2bf(v.x - bf2f(hv.x)), f2bf(v.y - bf2f(hv.y)),
                                      f2bf(v.z - bf2f(hv.z)), f2bf(v.w - bf2f(hv.w)) };
                const int lo = (((q - 4) * 2 + mt) * 64 + (i >> 1) * 16 + ml) * 8 + (i & 1) * 4;
                *reinterpret_cast<ushort4v*>(&AloF[lo]) = lv;
            }
        }
    }
    __syncthreads();

    const int w    = tid >> 6;
    const int lane = tid & 63;
    const int ml   = lane & 15;
    const int quad = lane >> 4;

    f32x4 acc[2][2][4];                  // [mt][jt][gate]
    #pragma unroll
    for (int mt = 0; mt < 2; ++mt)
        #pragma unroll
        for (int jt = 0; jt < 2; ++jt)
            #pragma unroll
            for (int g = 0; g < 4; ++g) acc[mt][jt][g] = (f32x4)0.f;

    const short8* Bh8 = reinterpret_cast<const short8*>(Bhi);
    const short8* Bl8 = reinterpret_cast<const short8*>(Blo);
    const short8* Ah8 = reinterpret_cast<const short8*>(AhiF);
    const short8* Al8 = reinterpret_cast<const short8*>(AloF);

    #pragma unroll
    for (int kb = 0; kb < 8; ++kb) {
        const short8 Ah0 = Ah8[(kb * 2 + 0) * 64 + lane];
        const short8 Ah1 = Ah8[(kb * 2 + 1) * 64 + lane];
        short8 Al0, Al1;
        if (kb >= 4) {
            Al0 = Al8[((kb - 4) * 2 + 0) * 64 + lane];
            Al1 = Al8[((kb - 4) * 2 + 1) * 64 + lane];
        }
        #pragma unroll
        for (int jt = 0; jt < 2; ++jt) {
            #pragma unroll
            for (int g = 0; g < 4; ++g) {
                const int tn = g * 8 + 2 * w + jt;
                const short8 Bh = Bh8[(kb * 32 + tn) * 64 + lane];
                if (kb < 4) {
                    acc[0][jt][g] = __builtin_amdgcn_mfma_f32_16x16x32_bf16(
                        Ah0, Bh, acc[0][jt][g], 0, 0, 0);
                    acc[1][jt][g] = __builtin_amdgcn_mfma_f32_16x16x32_bf16(
                        Ah1, Bh, acc[1][jt][g], 0, 0, 0);
                } else {
                    const short8 Bl = Bl8[((kb - 4) * 32 + tn) * 64 + lane];
                    acc[0][jt][g] = __builtin_amdgcn_mfma_f32_16x16x32_bf16(
                        Ah0, Bh, acc[0][jt][g], 0, 0, 0);
                    acc[0][jt][g] = __builtin_amdgcn_mfma_f32_16x16x32_bf16(
                        Ah0, Bl, acc[0][jt][g], 0, 0, 0);
                    acc[0][jt][g] = __builtin_amdgcn_mfma_f32_16x16x32_bf16(
                        Al0, Bh, acc[0][jt][g], 0, 0, 0);
                    acc[1][jt][g] = __builtin_amdgcn_mfma_f32_16x16x32_bf16(
                        Ah1, Bh, acc[1][jt][g], 0, 0, 0);
                    acc[1][jt][g] = __builtin_amdgcn_mfma_f32_16x16x32_bf16(
                        Ah1, Bl, acc[1][jt][g], 0, 0, 0);
                    acc[1][jt][g] = __builtin_amdgcn_mfma_f32_16x16x32_bf16(
                        Al1, Bh, acc[1][jt][g], 0, 0, 0);
                }
            }
        }
    }

    // ---- fused LSTM epilogue (C/D layout: row = quad*4+r, col = lane&15) ----
    #pragma unroll
    for (int jt = 0; jt < 2; ++jt) {
        const int j  = (2 * w + jt) * 16 + ml;
        const float bi = bias[j];
        const float bf = bias[128 + j];
        const float bg = bias[256 + j];
        const float bo = bias[384 + j];
        #pragma unroll
        for (int mt = 0; mt < 2; ++mt) {
            #pragma unroll
            for (int r = 0; r < 4; ++r) {
                const int m = m0 + mt * 16 + quad * 4 + r;
                const float ig = fsigmoid(acc[mt][jt][0][r] + bi);
                const float fg = fsigmoid(acc[mt][jt][1][r] + bf);
                const float gv = ftanh(acc[mt][jt][2][r] + bg);
                const float og = fsigmoid(acc[mt][jt][3][r] + bo);
                const float cp = c_prev[(size_t)(m >> 1) * D_N + j];
                const float cn = fg * cp + ig * gv;
                const float hn = og * ftanh(cn);
                c_cur[(size_t)m * D_N + j] = cn;
                h_cur[(size_t)m * D_N + j] = hn;
            }
        }
    }
}

// ---------------- final gather ----------------
__global__ __launch_bounds__(256) void gather_kernel(const float* __restrict__ h8,
                                                     const int* __restrict__ leaf,
                                                     float* __restrict__ out) {
    const int idx = blockIdx.x * 256 + threadIdx.x;
    const int k4  = idx & 31;
    const int bt  = idx >> 5;
    const int t   = bt % T_N;
    const int lf  = leaf[bt];
    float4 v = make_float4(0.f, 0.f, 0.f, 0.f);
    if (lf >= 0)
        v = reinterpret_cast<const float4*>(h8 + (size_t)(t * L_N + lf) * D_N)[k4];
    reinterpret_cast<float4*>(out)[idx] = v;
}

extern "C" void kernel_launch(void* const* d_in, const int* in_sizes, int n_in,
                              void* d_out, int out_size, void* d_ws, size_t ws_size,
                              hipStream_t stream) {
    const float* cross    = (const float*)d_in[0];
    const float* node_emb = (const float*)d_in[1];
    const float* w_ih     = (const float*)d_in[2];
    const float* w_hh     = (const float*)d_in[3];
    const float* b_ih     = (const float*)d_in[4];
    const float* b_hh     = (const float*)d_in[5];
    float* out = (float*)d_out;
    float* ws  = (float*)d_ws;

    // ws layout (floats): hA/cA (even levels), hB/cB (odd), leaf, bias, Bhi, Blo
    const size_t SA = (size_t)25600 * D_N;
    const size_t SB = (size_t)12800 * D_N;
    float* hA = ws;
    float* cA = hA + SA;
    float* hB = cA + SA;
    float* cB = hB + SB;
    int*   leaf = (int*)(cB + SB);
    float* bias = (float*)(leaf + 51200);
    unsigned short* Bhi = (unsigned short*)(bias + 512);
    unsigned short* Blo = Bhi + 131072;

    pack_kernel<<<512, 256, 0, stream>>>(w_ih, w_hh, b_ih, b_hh, Bhi, Blo, bias);
    leaf_kernel<<<(B_N * T_N) / 4, 256, 0, stream>>>(cross, leaf);

    // levels 0..4: fp32 vector kernel
    for (int d = 0; d <= 4; ++d) {
        const int M = T_N << d;
        float* hc = (d & 1) ? hB : hA;
        float* cc = (d & 1) ? cB : cA;
        float* hp = (d & 1) ? hA : hB;
        float* cp = (d & 1) ? cA : cB;
        dim3 grid((M + 63) / 64, D_N / 16);
        level_kernel<<<grid, 256, 0, stream>>>(node_emb, w_ih, w_hh, b_ih, b_hh,
                                               hp, cp, hc, cc, d, M);
    }
    // levels 5..8: MFMA split-bf16 kernel
    for (int d = 5; d <= 8; ++d) {
        const int M = T_N << d;
        float* hc = (d & 1) ? hB : hA;
        float* cc = (d & 1) ? cB : cA;
        float* hp = (d & 1) ? hA : hB;
        float* cp = (d & 1) ? cA : cB;
        mfma_level_kernel<<<M / 32, 256, 0, stream>>>(node_emb, Bhi, Blo, bias,
                                                      hp, cp, hc, cc, d);
    }
    // d=8 wrote hA
    gather_kernel<<<(B_N * T_N * (D_N / 4)) / 256, 256, 0, stream>>>(hA, leaf, out);
}